// Round 14
// baseline (113.270 us; speedup 1.0000x reference)
//
#include <hip/hip_runtime.h>
#include <math.h>

typedef float f32x4 __attribute__((ext_vector_type(4)));
typedef short s16x8 __attribute__((ext_vector_type(8)));

#define JT 64        // j-tiles (16 cols each) per block -> 1024 cols
#define WROWT 4      // row-tiles (16 rows each) per wave -> block = 256 rows
#define FBLOCKS 128

// ---- order-preserving float <-> uint key (works for negatives) ----
__device__ __forceinline__ unsigned f2key(float f) {
    unsigned b = __float_as_uint(f);
    return b ^ ((b & 0x80000000u) ? 0xFFFFFFFFu : 0x80000000u);
}
__device__ __forceinline__ float key2f(unsigned k) {
    unsigned b = k ^ ((k & 0x80000000u) ? 0x80000000u : 0xFFFFFFFFu);
    return __uint_as_float(b);
}
__device__ __forceinline__ float min3f(float a, float b, float c) {
    return fminf(fminf(a, b), c);   // -> v_min3_f32
}
__device__ __forceinline__ unsigned short bf16h(float f) {  // fp32 -> bf16 RNE
    unsigned u = __float_as_uint(f);
    return (unsigned short)((u + 0x7fffu + ((u >> 16) & 1u)) >> 16);
}
__device__ __forceinline__ float bf16f(unsigned short h) {
    return __uint_as_float(((unsigned)h) << 16);
}
__device__ __forceinline__ unsigned pk(unsigned short lo, unsigned short hi) {
    return (unsigned)lo | ((unsigned)hi << 16);
}

// Prep: build MFMA operand packs so that one mfma_f32_16x16x32_bf16 yields the
// FULL d = a^2 + b^2 - 2ab for a 16x16 tile. K-slot map (16 slots, quads 0-1):
//   A k: [xh xh xl xl | yh yh yl yl | zh zh zl zl | a2h a2l 1 1 ]
//   B k: [xh xl xh xl | yh yl yh yl | zh zl zh zl | 1  1  b2h b2l]  (b pre-scaled by -2)
// Each bf16xbf16 product is EXACT in fp32 (8-bit mantissas); only the split
// residuals (~2^-18 rel) are dropped -> |d_err| ~ 1e-5 << 9.3e-4 threshold.
// Pack layout: [b][tile][quad(2)][lane16] of 16B; lane l of any wave loads
// pack[(b*T+tile)*2+quad][l&15] (quads 2-3 are zero, not stored).
// Also initializes the 64k min-keys to 0xFF (replaces the memset dispatch).
__global__ __launch_bounds__(256) void prep_kernel(
    const float* __restrict__ arr1, const float* __restrict__ arr2,
    int N, int M, int Bb,
    uint4* __restrict__ apack, uint4* __restrict__ bpack,
    unsigned* __restrict__ keys)
{
    const int i = blockIdx.x * 256 + threadIdx.x;
    const int BN = Bb * N, BM = Bb * M;
    if (i < BN + BM) keys[i] = 0xFFFFFFFFu;
    if (i >= BN + BM) return;

    const bool isA = i < BN;
    const int p = isA ? i : i - BN;
    const int n = isA ? N : M;
    const float* src = (isA ? arr1 : arr2) + (size_t)p * 3;
    float x = src[0], y = src[1], z = src[2];
    float n2 = __builtin_fmaf(x, x, __builtin_fmaf(y, y, z * z));
    if (!isA) { x *= -2.0f; y *= -2.0f; z *= -2.0f; }

    unsigned short xh = bf16h(x),  xl = bf16h(x - bf16f(xh));
    unsigned short yh = bf16h(y),  yl = bf16h(y - bf16f(yh));
    unsigned short zh = bf16h(z),  zl = bf16h(z - bf16f(zh));
    unsigned short nh = bf16h(n2), nl = bf16h(n2 - bf16f(nh));
    const unsigned short one = 0x3F80;

    uint4 q0, q1;
    if (isA) {
        q0 = make_uint4(pk(xh, xh), pk(xl, xl), pk(yh, yh), pk(yl, yl));
        q1 = make_uint4(pk(zh, zh), pk(zl, zl), pk(nh, nl), pk(one, one));
    } else {
        q0 = make_uint4(pk(xh, xl), pk(xh, xl), pk(yh, yl), pk(yh, yl));
        q1 = make_uint4(pk(zh, zl), pk(zh, zl), pk(one, one), pk(nh, nl));
    }
    const int bI = p / n, pr = p % n;
    uint4* dst = (isA ? apack : bpack);
    const size_t base = ((size_t)(bI * (n >> 4) + (pr >> 4)) * 2) * 16 + (pr & 15);
    dst[base]      = q0;   // quad 0
    dst[base + 16] = q1;   // quad 1
}

// MFMA chamfer kernel. Block = 4 waves x WROWT row-tiles = 256 rows; sweeps
// JT=64 j-tiles (1024 cols). Per j-tile per wave: 1 B-frag load (L2-hot) +
// 4 MFMA (separate pipe) + pure-min epilogue (~2.2 VALU slots/pair vs 5.1 in
// the scalar kernel, which was pinned at ~44% issue across R4-R13 variants).
//   row mins: register accumulators, cross-lane xor-reduce once at end,
//             one atomicMin per row per block
//   col mins: per-lane fold + cross-quad shfl, staged in LDS per wave,
//             block fold -> one atomicMin per col per block
__global__ __launch_bounds__(256) void chamfer_mfma_kernel(
    const s16x8* __restrict__ apack, const s16x8* __restrict__ bpack,
    int N, int M,
    unsigned* __restrict__ rkey, unsigned* __restrict__ ckey,
    float* __restrict__ out)
{
    const int b    = blockIdx.z;
    const int wid  = threadIdx.x >> 6;
    const int lane = threadIdx.x & 63;
    const int quad = lane >> 4, l16 = lane & 15;

    if (blockIdx.x == 0 && blockIdx.y == 0 && b == 0 && threadIdx.x == 0)
        out[0] = 0.0f;

    __shared__ float cmin_lds[4][JT * 16];   // 16 KB

    // A-frags: wave wid owns row-tiles rt0..rt0+3 (rows blockIdx.x*256 + wid*64 ..)
    const int rt0 = blockIdx.x * 16 + wid * WROWT;
    s16x8 A[WROWT];
#pragma unroll
    for (int i = 0; i < WROWT; ++i) {
        if (quad < 2)
            A[i] = apack[((size_t)(b * (N >> 4) + rt0 + i) * 2 + quad) * 16 + l16];
        else
            A[i] = (s16x8)0;
    }

    float rmin[WROWT][4];
#pragma unroll
    for (int i = 0; i < WROWT; ++i)
#pragma unroll
        for (int r = 0; r < 4; ++r) rmin[i][r] = __builtin_inff();

    const f32x4 zf = {0.0f, 0.0f, 0.0f, 0.0f};

#pragma unroll 1
    for (int jt = 0; jt < JT; ++jt) {
        const int jtg = blockIdx.y * JT + jt;
        s16x8 Bf;
        if (quad < 2)
            Bf = bpack[((size_t)(b * (M >> 4) + jtg) * 2 + quad) * 16 + l16];
        else
            Bf = (s16x8)0;

        f32x4 a0 = __builtin_amdgcn_mfma_f32_16x16x32_bf16(A[0], Bf, zf, 0, 0, 0);
        f32x4 a1 = __builtin_amdgcn_mfma_f32_16x16x32_bf16(A[1], Bf, zf, 0, 0, 0);
        f32x4 a2 = __builtin_amdgcn_mfma_f32_16x16x32_bf16(A[2], Bf, zf, 0, 0, 0);
        f32x4 a3 = __builtin_amdgcn_mfma_f32_16x16x32_bf16(A[3], Bf, zf, 0, 0, 0);

        // Row mins: lane holds rows quad*4+r of each tile, col jtg*16+l16
#pragma unroll
        for (int r = 0; r < 4; ++r) {
            rmin[0][r] = fminf(rmin[0][r], a0[r]);
            rmin[1][r] = fminf(rmin[1][r], a1[r]);
            rmin[2][r] = fminf(rmin[2][r], a2[r]);
            rmin[3][r] = fminf(rmin[3][r], a3[r]);
        }
        // Col min over this wave's 64 rows: fold 16 accs, then cross-quad
        float m0 = fminf(min3f(a0[0], a0[1], a0[2]), a0[3]);
        float m1 = fminf(min3f(a1[0], a1[1], a1[2]), a1[3]);
        float m2 = fminf(min3f(a2[0], a2[1], a2[2]), a2[3]);
        float m3 = fminf(min3f(a3[0], a3[1], a3[2]), a3[3]);
        float cm = fminf(min3f(m0, m1, m2), m3);
        cm = fminf(cm, __shfl_xor(cm, 16, 64));
        cm = fminf(cm, __shfl_xor(cm, 32, 64));
        if (lane < 16) cmin_lds[wid][jt * 16 + lane] = cm;
    }

    // Cross-lane row reduce: 16 lanes of each quad hold the same rows
#pragma unroll
    for (int i = 0; i < WROWT; ++i)
#pragma unroll
        for (int r = 0; r < 4; ++r) {
            float v = rmin[i][r];
            v = fminf(v, __shfl_xor(v, 1, 64));
            v = fminf(v, __shfl_xor(v, 2, 64));
            v = fminf(v, __shfl_xor(v, 4, 64));
            v = fminf(v, __shfl_xor(v, 8, 64));
            rmin[i][r] = v;
        }
    if (l16 == 0) {
        unsigned* rk = rkey + (size_t)b * N + blockIdx.x * 256 + wid * (WROWT * 16);
#pragma unroll
        for (int i = 0; i < WROWT; ++i)
#pragma unroll
            for (int r = 0; r < 4; ++r)
                atomicMin(&rk[i * 16 + quad * 4 + r], f2key(rmin[i][r]));
    }

    __syncthreads();
    // Block col fold: 1024 cols, 4 wave-partials each -> one atomic per col
#pragma unroll
    for (int cc = 0; cc < 4; ++cc) {
        const int cl = threadIdx.x + cc * 256;
        float v = fminf(fminf(cmin_lds[0][cl], cmin_lds[1][cl]),
                        fminf(cmin_lds[2][cl], cmin_lds[3][cl]));
        atomicMin(&ckey[(size_t)b * M + blockIdx.y * (JT * 16) + cl], f2key(v));
    }
}

// Finalize: keys hold full d mins -> weighted sum, one atomicAdd per block.
__global__ __launch_bounds__(256) void chamfer_finalize_kernel(
    const unsigned* __restrict__ rkey, const unsigned* __restrict__ ckey,
    int BN, int BM, float* __restrict__ out)
{
    const float wA = 1.0f / (float)BN;
    const float wB = 1.0f / (float)BM;
    const int stride = 256 * FBLOCKS;

    float s = 0.0f;
    for (int i = blockIdx.x * 256 + threadIdx.x; i < BN; i += stride)
        s += wA * key2f(rkey[i]);
    for (int i = blockIdx.x * 256 + threadIdx.x; i < BM; i += stride)
        s += wB * key2f(ckey[i]);

#pragma unroll
    for (int off = 32; off > 0; off >>= 1)
        s += __shfl_down(s, off, 64);

    __shared__ float wsum[4];
    int lane = threadIdx.x & 63, wv = threadIdx.x >> 6;
    if (lane == 0) wsum[wv] = s;
    __syncthreads();
    if (threadIdx.x == 0)
        atomicAdd(out, wsum[0] + wsum[1] + wsum[2] + wsum[3]);
}

extern "C" void kernel_launch(void* const* d_in, const int* in_sizes, int n_in,
                              void* d_out, int out_size, void* d_ws, size_t ws_size,
                              hipStream_t stream)
{
    const float* arr1 = (const float*)d_in[0];
    const float* arr2 = (const float*)d_in[1];
    float* out = (float*)d_out;

    const int Bb = 4;
    const int N = in_sizes[0] / (Bb * 3);   // 8192
    const int M = in_sizes[1] / (Bb * 3);   // 8192
    const int BN = Bb * N, BM = Bb * M;

    // ws: [rkey BN][ckey BM][apack 1MB][bpack 1MB]
    unsigned* rkey = (unsigned*)d_ws;
    unsigned* ckey = rkey + BN;
    uint4* apack = (uint4*)((char*)d_ws + (size_t)(BN + BM) * sizeof(unsigned));
    uint4* bpack = apack + (size_t)Bb * (N >> 4) * 2 * 16;

    prep_kernel<<<(BN + BM) / 256, 256, 0, stream>>>(
        arr1, arr2, N, M, Bb, apack, bpack, rkey);

    dim3 grid(N / 256, M / (JT * 16), Bb);   // (32, 8, 4) = 1024 blocks
    chamfer_mfma_kernel<<<grid, 256, 0, stream>>>(
        (const s16x8*)apack, (const s16x8*)bpack, N, M, rkey, ckey, out);

    chamfer_finalize_kernel<<<FBLOCKS, 256, 0, stream>>>(rkey, ckey, BN, BM, out);
}